// Round 5
// baseline (219.766 us; speedup 1.0000x reference)
//
#include <hip/hip_runtime.h>

// Malvar-He-Cutler demosaic, RGGB, reflect-101, fp32.
// Each block: ONE ROW PAIR (y0 even, y0+1) of one image; 256 threads x 8 px.
// 6-row input window; vertical sums factorized; nontemporal float4 stores.
// XCD-chunked swizzle keeps each XCD on a contiguous band of row pairs.

typedef float f32x4 __attribute__((ext_vector_type(4)));

__device__ __forceinline__ int reflect_idx(int i, int n) {
    // jnp.pad mode='reflect': -1 -> 1, -2 -> 2, n -> n-2, n+1 -> n-3
    if (i < 0) i = -i;
    if (i >= n) i = 2 * n - 2 - i;
    return i;
}

__device__ __forceinline__ float clip01(float x) {
    return fminf(fmaxf(x, 0.0f), 1.0f);
}

__device__ __forceinline__ void nt_store4(float* p, float a, float b, float c, float d) {
    f32x4 v = {a, b, c, d};
    __builtin_nontemporal_store(v, (f32x4*)p);
}

// Load 12-col window (cols x0-2 .. x0+9) of one input row into w[12].
__device__ __forceinline__ void load_row12(const float* __restrict__ row,
                                           int x0, int W, float w[12]) {
    const bool left  = (x0 == 0);
    const bool right = (x0 + 8 >= W);
    const int xl = left ? 0 : x0 - 4;
    const int xr = right ? W - 4 : x0 + 8;
    const float4 L  = *(const float4*)(row + xl);
    const float4 A  = *(const float4*)(row + x0);
    const float4 Bv = *(const float4*)(row + x0 + 4);
    const float4 R  = *(const float4*)(row + xr);
    w[2] = A.x;  w[3] = A.y;  w[4] = A.z;  w[5] = A.w;
    w[6] = Bv.x; w[7] = Bv.y; w[8] = Bv.z; w[9] = Bv.w;
    // reflect-101 at row ends resolved from registers
    w[0]  = left  ? A.z  : L.z;   // col -2 -> 2
    w[1]  = left  ? A.y  : L.w;   // col -1 -> 1
    w[10] = right ? Bv.z : R.x;   // col W -> W-2
    w[11] = right ? Bv.y : R.y;   // col W+1 -> W-3
}

// Emit one output row of 8 pixels. C = center row window, V13 = rows +-1 sum,
// V04 = rows +-2 sum. EVEN_ROW selects R/Gr vs Gb/B channel assignment.
// ce = column where the R-or-B-site stencils (gatrb, brv) are evaluated;
// co = column where the G-site stencils (colv, rowv) are evaluated.
template <bool EVEN_ROW>
__device__ __forceinline__ void emit_row(
    const float C[12], const float V13[12], const float V04[12],
    float* __restrict__ o, size_t plane) {
    float r[8], g[8], bl[8];
#pragma unroll
    for (int k = 0; k < 8; k += 2) {
        const int c  = k + 2;
        const int ce = EVEN_ROW ? c : c + 1;   // R/B raw-sample column
        const int co = EVEN_ROW ? c + 1 : c;   // G raw-sample column
        // stencils at the R/B site (ce)
        const float t2 = V04[ce] + C[ce - 2] + C[ce + 2];
        const float gatrb = 0.5f * C[ce]
                          + 0.25f * (V13[ce] + C[ce - 1] + C[ce + 1])
                          - 0.125f * t2;
        const float brv   = 0.75f * C[ce]
                          + 0.25f * (V13[ce - 1] + V13[ce + 1])
                          - 0.1875f * t2;
        // stencils at the G site (co)
        const float t4 = C[co - 1] + C[co + 1];
        const float t5 = V13[co - 1] + V13[co + 1];
        const float t6 = C[co - 2] + C[co + 2];
        const float colv = 0.625f * C[co] + 0.5f * t4
                         - 0.125f * (t5 + t6) + 0.0625f * V04[co];
        const float rowv = 0.625f * C[co] + 0.5f * V13[co]
                         - 0.125f * t5 - 0.125f * V04[co] + 0.0625f * t6;
        if (EVEN_ROW) {
            // even col = R site, odd col = Gr site
            r[k] = C[c];      g[k] = gatrb;        bl[k] = brv;
            r[k + 1] = colv;  g[k + 1] = C[c + 1]; bl[k + 1] = rowv;
        } else {
            // even col = Gb site, odd col = B site
            r[k] = rowv;      g[k] = C[c];         bl[k] = colv;
            r[k + 1] = brv;   g[k + 1] = gatrb;    bl[k + 1] = C[c + 1];
        }
    }
    nt_store4(o,     clip01(r[0]), clip01(r[1]), clip01(r[2]), clip01(r[3]));
    nt_store4(o + 4, clip01(r[4]), clip01(r[5]), clip01(r[6]), clip01(r[7]));
    float* og = o + plane;
    nt_store4(og,     clip01(g[0]), clip01(g[1]), clip01(g[2]), clip01(g[3]));
    nt_store4(og + 4, clip01(g[4]), clip01(g[5]), clip01(g[6]), clip01(g[7]));
    float* ob = o + 2 * plane;
    nt_store4(ob,     clip01(bl[0]), clip01(bl[1]), clip01(bl[2]), clip01(bl[3]));
    nt_store4(ob + 4, clip01(bl[4]), clip01(bl[5]), clip01(bl[6]), clip01(bl[7]));
}

__global__ __launch_bounds__(256) void demosaic_kernel(
    const float* __restrict__ bayer, float* __restrict__ out, int H, int W) {
    // XCD-chunked swizzle (gridDim.x divisible by 8)
    const int bid = blockIdx.x;
    const int chunk = gridDim.x >> 3;
    const int swz = (bid & 7) * chunk + (bid >> 3);
    const int Hp = H >> 1;
    const int b = swz / Hp;
    const int y0 = (swz - b * Hp) << 1;  // even output row

    const int x0 = (int)threadIdx.x << 3;  // 8 px per thread
    const size_t plane = (size_t)H * W;
    const float* src = bayer + (size_t)b * plane;

    // input rows y0-2 .. y0+3 (a..f), reflected at image top/bottom
    float ra[12], rbv[12], rc[12], rd[12], re[12], rf[12];
    load_row12(src + (size_t)reflect_idx(y0 - 2, H) * W, x0, W, ra);
    load_row12(src + (size_t)reflect_idx(y0 - 1, H) * W, x0, W, rbv);
    load_row12(src + (size_t)y0 * W, x0, W, rc);
    load_row12(src + (size_t)(y0 + 1) * W, x0, W, rd);
    load_row12(src + (size_t)reflect_idx(y0 + 2, H) * W, x0, W, re);
    load_row12(src + (size_t)reflect_idx(y0 + 3, H) * W, x0, W, rf);

    float* o0 = out + (size_t)b * 3 * plane + (size_t)y0 * W + x0;

    // even row y0: C=rc, V13=b+d, V04=a+e
    float v13[12], v04[12];
#pragma unroll
    for (int i = 0; i < 12; ++i) { v13[i] = rbv[i] + rd[i]; v04[i] = ra[i] + re[i]; }
    emit_row<true>(rc, v13, v04, o0, plane);

    // odd row y0+1: C=rd, V13=c+e, V04=b+f
#pragma unroll
    for (int i = 0; i < 12; ++i) { v13[i] = rc[i] + re[i]; v04[i] = rbv[i] + rf[i]; }
    emit_row<false>(rd, v13, v04, o0 + W, plane);
}

extern "C" void kernel_launch(void* const* d_in, const int* in_sizes, int n_in,
                              void* d_out, int out_size, void* d_ws, size_t ws_size,
                              hipStream_t stream) {
    const float* bayer = (const float*)d_in[0];
    float* out = (float*)d_out;

    const int H = 2048, W = 2048;
    const int B = in_sizes[0] / (H * W);

    dim3 block(256, 1, 1);
    dim3 grid(B * (H >> 1), 1, 1);  // one block per row pair
    demosaic_kernel<<<grid, block, 0, stream>>>(bayer, out, H, W);
}

// Round 6
// 158.513 us; speedup vs baseline: 1.3864x; 1.3864x over previous
//
#include <hip/hip_runtime.h>

// Malvar-He-Cutler demosaic, RGGB, reflect-101, fp32.
// Each block: ONE ROW PAIR (y0 even, y0+1) of one image; 256 threads x 8 px.
// 6-row input window; vertical sums factorized; PLAIN float4 stores
// (nontemporal stores measured 1.5x write amplification on gfx950 - reverted).
// XCD-chunked swizzle keeps each XCD on a contiguous band of row pairs.

__device__ __forceinline__ int reflect_idx(int i, int n) {
    // jnp.pad mode='reflect': -1 -> 1, -2 -> 2, n -> n-2, n+1 -> n-3
    if (i < 0) i = -i;
    if (i >= n) i = 2 * n - 2 - i;
    return i;
}

__device__ __forceinline__ float clip01(float x) {
    return fminf(fmaxf(x, 0.0f), 1.0f);
}

// Load 12-col window (cols x0-2 .. x0+9) of one input row into w[12].
__device__ __forceinline__ void load_row12(const float* __restrict__ row,
                                           int x0, int W, float w[12]) {
    const bool left  = (x0 == 0);
    const bool right = (x0 + 8 >= W);
    const int xl = left ? 0 : x0 - 4;
    const int xr = right ? W - 4 : x0 + 8;
    const float4 L  = *(const float4*)(row + xl);
    const float4 A  = *(const float4*)(row + x0);
    const float4 Bv = *(const float4*)(row + x0 + 4);
    const float4 R  = *(const float4*)(row + xr);
    w[2] = A.x;  w[3] = A.y;  w[4] = A.z;  w[5] = A.w;
    w[6] = Bv.x; w[7] = Bv.y; w[8] = Bv.z; w[9] = Bv.w;
    // reflect-101 at row ends resolved from registers
    w[0]  = left  ? A.z  : L.z;   // col -2 -> 2
    w[1]  = left  ? A.y  : L.w;   // col -1 -> 1
    w[10] = right ? Bv.z : R.x;   // col W -> W-2
    w[11] = right ? Bv.y : R.y;   // col W+1 -> W-3
}

// Emit one output row of 8 pixels. C = center row window, V13 = rows +-1 sum,
// V04 = rows +-2 sum. EVEN_ROW selects R/Gr vs Gb/B channel assignment.
// ce = column of the R-or-B raw sample; co = column of the G raw sample.
template <bool EVEN_ROW>
__device__ __forceinline__ void emit_row(
    const float C[12], const float V13[12], const float V04[12],
    float* __restrict__ o, size_t plane) {
    float r[8], g[8], bl[8];
#pragma unroll
    for (int k = 0; k < 8; k += 2) {
        const int c  = k + 2;
        const int ce = EVEN_ROW ? c : c + 1;   // R/B raw-sample column
        const int co = EVEN_ROW ? c + 1 : c;   // G raw-sample column
        // stencils at the R/B site (ce)
        const float t2 = V04[ce] + C[ce - 2] + C[ce + 2];
        const float gatrb = 0.5f * C[ce]
                          + 0.25f * (V13[ce] + C[ce - 1] + C[ce + 1])
                          - 0.125f * t2;
        const float brv   = 0.75f * C[ce]
                          + 0.25f * (V13[ce - 1] + V13[ce + 1])
                          - 0.1875f * t2;
        // stencils at the G site (co)
        const float t4 = C[co - 1] + C[co + 1];
        const float t5 = V13[co - 1] + V13[co + 1];
        const float t6 = C[co - 2] + C[co + 2];
        const float colv = 0.625f * C[co] + 0.5f * t4
                         - 0.125f * (t5 + t6) + 0.0625f * V04[co];
        const float rowv = 0.625f * C[co] + 0.5f * V13[co]
                         - 0.125f * t5 - 0.125f * V04[co] + 0.0625f * t6;
        if (EVEN_ROW) {
            // even col = R site, odd col = Gr site
            r[k] = C[c];      g[k] = gatrb;        bl[k] = brv;
            r[k + 1] = colv;  g[k + 1] = C[c + 1]; bl[k + 1] = rowv;
        } else {
            // even col = Gb site, odd col = B site
            r[k] = rowv;      g[k] = C[c];         bl[k] = colv;
            r[k + 1] = brv;   g[k + 1] = gatrb;    bl[k + 1] = C[c + 1];
        }
    }
    *(float4*)(o)     = make_float4(clip01(r[0]), clip01(r[1]), clip01(r[2]), clip01(r[3]));
    *(float4*)(o + 4) = make_float4(clip01(r[4]), clip01(r[5]), clip01(r[6]), clip01(r[7]));
    float* og = o + plane;
    *(float4*)(og)     = make_float4(clip01(g[0]), clip01(g[1]), clip01(g[2]), clip01(g[3]));
    *(float4*)(og + 4) = make_float4(clip01(g[4]), clip01(g[5]), clip01(g[6]), clip01(g[7]));
    float* ob = o + 2 * plane;
    *(float4*)(ob)     = make_float4(clip01(bl[0]), clip01(bl[1]), clip01(bl[2]), clip01(bl[3]));
    *(float4*)(ob + 4) = make_float4(clip01(bl[4]), clip01(bl[5]), clip01(bl[6]), clip01(bl[7]));
}

__global__ __launch_bounds__(256) void demosaic_kernel(
    const float* __restrict__ bayer, float* __restrict__ out, int H, int W) {
    // XCD-chunked swizzle (gridDim.x divisible by 8)
    const int bid = blockIdx.x;
    const int chunk = gridDim.x >> 3;
    const int swz = (bid & 7) * chunk + (bid >> 3);
    const int Hp = H >> 1;
    const int b = swz / Hp;
    const int y0 = (swz - b * Hp) << 1;  // even output row

    const int x0 = (int)threadIdx.x << 3;  // 8 px per thread
    const size_t plane = (size_t)H * W;
    const float* src = bayer + (size_t)b * plane;

    // input rows y0-2 .. y0+3 (a..f), reflected at image top/bottom
    float ra[12], rbv[12], rc[12], rd[12], re[12], rf[12];
    load_row12(src + (size_t)reflect_idx(y0 - 2, H) * W, x0, W, ra);
    load_row12(src + (size_t)reflect_idx(y0 - 1, H) * W, x0, W, rbv);
    load_row12(src + (size_t)y0 * W, x0, W, rc);
    load_row12(src + (size_t)(y0 + 1) * W, x0, W, rd);
    load_row12(src + (size_t)reflect_idx(y0 + 2, H) * W, x0, W, re);
    load_row12(src + (size_t)reflect_idx(y0 + 3, H) * W, x0, W, rf);

    float* o0 = out + (size_t)b * 3 * plane + (size_t)y0 * W + x0;

    // even row y0: C=rc, V13=b+d, V04=a+e
    float v13[12], v04[12];
#pragma unroll
    for (int i = 0; i < 12; ++i) { v13[i] = rbv[i] + rd[i]; v04[i] = ra[i] + re[i]; }
    emit_row<true>(rc, v13, v04, o0, plane);

    // odd row y0+1: C=rd, V13=c+e, V04=b+f
#pragma unroll
    for (int i = 0; i < 12; ++i) { v13[i] = rc[i] + re[i]; v04[i] = rbv[i] + rf[i]; }
    emit_row<false>(rd, v13, v04, o0 + W, plane);
}

extern "C" void kernel_launch(void* const* d_in, const int* in_sizes, int n_in,
                              void* d_out, int out_size, void* d_ws, size_t ws_size,
                              hipStream_t stream) {
    const float* bayer = (const float*)d_in[0];
    float* out = (float*)d_out;

    const int H = 2048, W = 2048;
    const int B = in_sizes[0] / (H * W);

    dim3 block(256, 1, 1);
    dim3 grid(B * (H >> 1), 1, 1);  // one block per row pair
    demosaic_kernel<<<grid, block, 0, stream>>>(bayer, out, H, W);
}

// Round 7
// 155.562 us; speedup vs baseline: 1.4127x; 1.0190x over previous
//
#include <hip/hip_runtime.h>

// Malvar-He-Cutler demosaic, RGGB, reflect-101, fp32.
// Sliding-window y-coarsened: one block = 8 output rows (4 row pairs) of one
// full-width row strip; 256 threads x 8 px. Register ring of 8 row-windows;
// next pair's 2 rows are prefetched before computing the current pair
// (software pipeline). Plain float4 stores (NT stores: 1.5x write amp, R5).
// XCD-chunked swizzle: each XCD gets a contiguous band (here: one image).

#define ROWS_PER_BLOCK 8  // 4 row pairs

__device__ __forceinline__ int reflect_idx(int i, int n) {
    // jnp.pad mode='reflect': -1 -> 1, -2 -> 2, n -> n-2, n+1 -> n-3
    if (i < 0) i = -i;
    if (i >= n) i = 2 * n - 2 - i;
    return i;
}

__device__ __forceinline__ float clip01(float x) {
    return fminf(fmaxf(x, 0.0f), 1.0f);
}

// Load 12-col window (cols x0-2 .. x0+9) of one input row into w[12].
__device__ __forceinline__ void load_row12(const float* __restrict__ row,
                                           int x0, int W, float w[12]) {
    const bool left  = (x0 == 0);
    const bool right = (x0 + 8 >= W);
    const int xl = left ? 0 : x0 - 4;
    const int xr = right ? W - 4 : x0 + 8;
    const float4 L  = *(const float4*)(row + xl);
    const float4 A  = *(const float4*)(row + x0);
    const float4 Bv = *(const float4*)(row + x0 + 4);
    const float4 R  = *(const float4*)(row + xr);
    w[2] = A.x;  w[3] = A.y;  w[4] = A.z;  w[5] = A.w;
    w[6] = Bv.x; w[7] = Bv.y; w[8] = Bv.z; w[9] = Bv.w;
    // reflect-101 at row ends resolved from registers
    w[0]  = left  ? A.z  : L.z;   // col -2 -> 2
    w[1]  = left  ? A.y  : L.w;   // col -1 -> 1
    w[10] = right ? Bv.z : R.x;   // col W -> W-2
    w[11] = right ? Bv.y : R.y;   // col W+1 -> W-3
}

// Emit one output row of 8 pixels. C = center row window, V13 = rows +-1 sum,
// V04 = rows +-2 sum. EVEN_ROW selects R/Gr vs Gb/B channel assignment.
template <bool EVEN_ROW>
__device__ __forceinline__ void emit_row(
    const float C[12], const float V13[12], const float V04[12],
    float* __restrict__ o, size_t plane) {
    float r[8], g[8], bl[8];
#pragma unroll
    for (int k = 0; k < 8; k += 2) {
        const int c  = k + 2;
        const int ce = EVEN_ROW ? c : c + 1;   // R/B raw-sample column
        const int co = EVEN_ROW ? c + 1 : c;   // G raw-sample column
        // stencils at the R/B site (ce)
        const float t2 = V04[ce] + C[ce - 2] + C[ce + 2];
        const float gatrb = 0.5f * C[ce]
                          + 0.25f * (V13[ce] + C[ce - 1] + C[ce + 1])
                          - 0.125f * t2;
        const float brv   = 0.75f * C[ce]
                          + 0.25f * (V13[ce - 1] + V13[ce + 1])
                          - 0.1875f * t2;
        // stencils at the G site (co)
        const float t4 = C[co - 1] + C[co + 1];
        const float t5 = V13[co - 1] + V13[co + 1];
        const float t6 = C[co - 2] + C[co + 2];
        const float colv = 0.625f * C[co] + 0.5f * t4
                         - 0.125f * (t5 + t6) + 0.0625f * V04[co];
        const float rowv = 0.625f * C[co] + 0.5f * V13[co]
                         - 0.125f * t5 - 0.125f * V04[co] + 0.0625f * t6;
        if (EVEN_ROW) {
            // even col = R site, odd col = Gr site
            r[k] = C[c];      g[k] = gatrb;        bl[k] = brv;
            r[k + 1] = colv;  g[k + 1] = C[c + 1]; bl[k + 1] = rowv;
        } else {
            // even col = Gb site, odd col = B site
            r[k] = rowv;      g[k] = C[c];         bl[k] = colv;
            r[k + 1] = brv;   g[k + 1] = gatrb;    bl[k + 1] = C[c + 1];
        }
    }
    *(float4*)(o)     = make_float4(clip01(r[0]), clip01(r[1]), clip01(r[2]), clip01(r[3]));
    *(float4*)(o + 4) = make_float4(clip01(r[4]), clip01(r[5]), clip01(r[6]), clip01(r[7]));
    float* og = o + plane;
    *(float4*)(og)     = make_float4(clip01(g[0]), clip01(g[1]), clip01(g[2]), clip01(g[3]));
    *(float4*)(og + 4) = make_float4(clip01(g[4]), clip01(g[5]), clip01(g[6]), clip01(g[7]));
    float* ob = o + 2 * plane;
    *(float4*)(ob)     = make_float4(clip01(bl[0]), clip01(bl[1]), clip01(bl[2]), clip01(bl[3]));
    *(float4*)(ob + 4) = make_float4(clip01(bl[4]), clip01(bl[5]), clip01(bl[6]), clip01(bl[7]));
}

__global__ __launch_bounds__(256, 3) void demosaic_kernel(
    const float* __restrict__ bayer, float* __restrict__ out, int H, int W) {
    // XCD-chunked swizzle (gridDim.x divisible by 8)
    const int bid = blockIdx.x;
    const int chunk = gridDim.x >> 3;
    const int swz = (bid & 7) * chunk + (bid >> 3);
    const int Hb = H / ROWS_PER_BLOCK;     // blocks per image
    const int b = swz / Hb;
    const int y0 = (swz - b * Hb) * ROWS_PER_BLOCK;

    const int x0 = (int)threadIdx.x << 3;  // 8 px per thread
    const size_t plane = (size_t)H * W;
    const float* src = bayer + (size_t)b * plane;

    // ring of 8 row windows; rows y0-2 .. y0+3 fill w[0..5]
    float w[8][12];
#pragma unroll
    for (int i = 0; i < 6; ++i)
        load_row12(src + (size_t)reflect_idx(y0 - 2 + i, H) * W, x0, W, w[i]);

    float* o = out + (size_t)b * 3 * plane + (size_t)y0 * W + x0;

    float v13[12], v04[12];
#pragma unroll
    for (int p = 0; p < ROWS_PER_BLOCK / 2; ++p) {
        // prefetch the next pair's two rows into the ring (overlaps compute)
        if (p < ROWS_PER_BLOCK / 2 - 1) {
            load_row12(src + (size_t)reflect_idx(y0 + 4 + 2 * p, H) * W, x0, W,
                       w[(6 + 2 * p) & 7]);
            load_row12(src + (size_t)reflect_idx(y0 + 5 + 2 * p, H) * W, x0, W,
                       w[(7 + 2 * p) & 7]);
        }
        const int i0 = (2 * p) & 7, i1 = (2 * p + 1) & 7, i2 = (2 * p + 2) & 7;
        const int i3 = (2 * p + 3) & 7, i4 = (2 * p + 4) & 7, i5 = (2 * p + 5) & 7;
        // even row: C=w[i2], V13=w[i1]+w[i3], V04=w[i0]+w[i4]
#pragma unroll
        for (int i = 0; i < 12; ++i) { v13[i] = w[i1][i] + w[i3][i]; v04[i] = w[i0][i] + w[i4][i]; }
        emit_row<true>(w[i2], v13, v04, o, plane);
        // odd row: C=w[i3], V13=w[i2]+w[i4], V04=w[i1]+w[i5]
#pragma unroll
        for (int i = 0; i < 12; ++i) { v13[i] = w[i2][i] + w[i4][i]; v04[i] = w[i1][i] + w[i5][i]; }
        emit_row<false>(w[i3], v13, v04, o + W, plane);
        o += 2 * W;
    }
}

extern "C" void kernel_launch(void* const* d_in, const int* in_sizes, int n_in,
                              void* d_out, int out_size, void* d_ws, size_t ws_size,
                              hipStream_t stream) {
    const float* bayer = (const float*)d_in[0];
    float* out = (float*)d_out;

    const int H = 2048, W = 2048;
    const int B = in_sizes[0] / (H * W);

    dim3 block(256, 1, 1);
    dim3 grid(B * (H / ROWS_PER_BLOCK), 1, 1);
    demosaic_kernel<<<grid, block, 0, stream>>>(bayer, out, H, W);
}